// Round 12
// baseline (75.141 us; speedup 1.0000x reference)
//
#include <hip/hip_runtime.h>
#include <cfloat>
#include <cstdint>

#define GBM 64
#define GBN 64
#define GBK 64
#define GPAD 68     // 68*4=272B rows: 16B-aligned for b128 frags

#define G_    169
#define D_    1024
#define H_    512
#define SPL   8     // split-K slices

typedef unsigned int u32;

// ---- split-K GEMM: py[s][M][N] partial of A[M,K] @ B[K,N], one 64^3 tile/block
__global__ __launch_bounds__(256) void gemm_splitk(
    const float* __restrict__ A, const float* __restrict__ B,
    float* __restrict__ Cpart, int M, int N, int K)
{
    __shared__ __align__(16) float Asm[GBK][GPAD];
    __shared__ __align__(16) float Bsm[GBK][GPAD];
    int t  = threadIdx.x;
    int m0 = blockIdx.y * GBM, n0 = blockIdx.x * GBN;
    int ks = blockIdx.z * GBK;

    #pragma unroll
    for (int i = 0; i < 4; i++) {
        int v = t + 256 * i;
        int m = v >> 4, k4 = (v & 15) * 4;
        float4 x = *(const float4*)&A[(size_t)(m0 + m) * K + ks + k4];
        Asm[k4 + 0][m] = x.x; Asm[k4 + 1][m] = x.y;
        Asm[k4 + 2][m] = x.z; Asm[k4 + 3][m] = x.w;
    }
    #pragma unroll
    for (int i = 0; i < 4; i++) {
        int v = t + 256 * i;
        int r = v >> 4, c4 = (v & 15) * 4;
        *(float4*)&Bsm[r][c4] = *(const float4*)&B[(size_t)(ks + r) * N + n0 + c4];
    }
    __syncthreads();

    int r4 = (t >> 4) * 4, c4 = (t & 15) * 4;
    float acc[4][4] = {{0.f}};
    #pragma unroll
    for (int kk = 0; kk < GBK; kk++) {
        float4 a = *(const float4*)&Asm[kk][r4];
        float4 b = *(const float4*)&Bsm[kk][c4];
        float av[4] = {a.x, a.y, a.z, a.w};
        float bv[4] = {b.x, b.y, b.z, b.w};
        #pragma unroll
        for (int i = 0; i < 4; i++)
            #pragma unroll
            for (int j = 0; j < 4; j++) acc[i][j] += av[i] * bv[j];
    }
    float* Cp = Cpart + (size_t)blockIdx.z * M * N;
    #pragma unroll
    for (int i = 0; i < 4; i++) {
        float4 v = {acc[i][0], acc[i][1], acc[i][2], acc[i][3]};
        *(float4*)&Cp[(size_t)(m0 + r4 + i) * N + n0 + c4] = v;
    }
}

// ---- gemm2: pz[s][M][N] partial of (sum_s py + b_ts)[M,K] @ W[N,K]^T -------
__global__ __launch_bounds__(256) void gemm2_fused(
    const float* __restrict__ py, const float* __restrict__ b_ts,
    const float* __restrict__ W, float* __restrict__ pz,
    int M, int N, int K)
{
    __shared__ __align__(16) float Asm[GBK][GPAD];
    __shared__ __align__(16) float Bsm[GBK][GPAD];
    int t  = threadIdx.x;
    int m0 = blockIdx.y * GBM, n0 = blockIdx.x * GBN;
    int ks = blockIdx.z * GBK;

    #pragma unroll
    for (int i = 0; i < 4; i++) {                    // A = reduced y tile
        int v = t + 256 * i;
        int m = v >> 4, h4 = (v & 15) * 4;
        float4 x = *(const float4*)&b_ts[ks + h4];
        #pragma unroll
        for (int s = 0; s < SPL; s++) {              // 8 independent loads
            float4 p = *(const float4*)&py[((size_t)s * M + m0 + m) * K + ks + h4];
            x.x += p.x; x.y += p.y; x.z += p.z; x.w += p.w;
        }
        Asm[h4 + 0][m] = x.x; Asm[h4 + 1][m] = x.y;
        Asm[h4 + 2][m] = x.z; Asm[h4 + 3][m] = x.w;
    }
    #pragma unroll
    for (int i = 0; i < 4; i++) {                    // B^T tile
        int v = t + 256 * i;
        int n = v >> 4, k4 = (v & 15) * 4;
        float4 x = *(const float4*)&W[(size_t)(n0 + n) * K + ks + k4];
        Bsm[k4 + 0][n] = x.x; Bsm[k4 + 1][n] = x.y;
        Bsm[k4 + 2][n] = x.z; Bsm[k4 + 3][n] = x.w;
    }
    __syncthreads();

    int r4 = (t >> 4) * 4, c4 = (t & 15) * 4;
    float acc[4][4] = {{0.f}};
    #pragma unroll
    for (int kk = 0; kk < GBK; kk++) {
        float4 a = *(const float4*)&Asm[kk][r4];
        float4 b = *(const float4*)&Bsm[kk][c4];
        float av[4] = {a.x, a.y, a.z, a.w};
        float bv[4] = {b.x, b.y, b.z, b.w};
        #pragma unroll
        for (int i = 0; i < 4; i++)
            #pragma unroll
            for (int j = 0; j < 4; j++) acc[i][j] += av[i] * bv[j];
    }
    float* Cp = pz + (size_t)blockIdx.z * M * N;
    #pragma unroll
    for (int i = 0; i < 4; i++) {
        float4 v = {acc[i][0], acc[i][1], acc[i][2], acc[i][3]};
        *(float4*)&Cp[(size_t)(m0 + r4 + i) * N + n0 + c4] = v;
    }
}

// ---- feat.z for ALL grids of one batch + in-block finalize -----------------
// One block per batch, 512 threads = 8 waves, wave w owns rows [128w,128w+128).
// Per-lane register loads (no feat LDS, no DMA): 24 coalesced dword loads per
// 8-row body; z broadcast via wave-uniform ds_read_b128. TLP hides latency.
__global__ __launch_bounds__(512) void feat_final(
    const float* __restrict__ feat, const float* __restrict__ pz,
    const float* __restrict__ boxes, const float* __restrict__ masks,
    const float* __restrict__ py, const float* __restrict__ b_ts,
    const float* __restrict__ b_vs, const int* __restrict__ kptr,
    float* __restrict__ out_box, float* __restrict__ out_mask,
    float* __restrict__ out_max,
    int bs, int AN, int CH, int CM)
{
    __shared__ __align__(16) float zs[D_];
    __shared__ float accw[8 * 176];
    __shared__ float simall[176];
    __shared__ float ms[176];
    __shared__ int   selg[176];
    __shared__ float simv[176];
    __shared__ float redw[8];
    __shared__ float bbs;
    __shared__ int   selp[2];

    const int b = blockIdx.x;
    const int t = threadIdx.x;
    const int w = t >> 6, lane = t & 63;

    // zs = sum_s pz[s][b]
    {
        int h2 = t * 2;
        float2 s = {0.f, 0.f};
        #pragma unroll
        for (int sp = 0; sp < SPL; sp++) {
            float2 v = *(const float2*)&pz[((size_t)sp * bs + b) * D_ + h2];
            s.x += v.x; s.y += v.y;
        }
        *(float2*)&zs[h2] = s;
    }
    __syncthreads();

    // wave w: rows [w*128, w*128+128)
    const float* rp = feat + ((size_t)b * D_ + (size_t)w * 128) * G_;
    float acc0 = 0.f, acc1 = 0.f, acc2 = 0.f;
    const bool g2 = lane < (G_ - 128);   // 41 lanes
    for (int gi = 0; gi < 16; gi++) {
        float4 zq0 = *(const float4*)&zs[w * 128 + gi * 8];      // broadcast
        float4 zq1 = *(const float4*)&zs[w * 128 + gi * 8 + 4];  // broadcast
        float zarr[8] = {zq0.x, zq0.y, zq0.z, zq0.w, zq1.x, zq1.y, zq1.z, zq1.w};
        const float* base = rp + (size_t)gi * 8 * G_;
        #pragma unroll
        for (int r = 0; r < 8; r++) {
            const float* rr = base + r * G_;
            float zv = zarr[r];
            acc0 += rr[lane] * zv;
            acc1 += rr[lane + 64] * zv;
            if (g2) acc2 += rr[lane + 128] * zv;
        }
    }
    accw[w * 176 + lane]      = acc0;
    accw[w * 176 + lane + 64] = acc1;
    if (g2) accw[w * 176 + lane + 128] = acc2;
    __syncthreads();

    // ======================= finalize for batch b =========================
    int k = *kptr; if (k > G_) k = G_;

    if (t < G_) {
        float s = 0.f;
        #pragma unroll
        for (int ww = 0; ww < 8; ww++) s += accw[ww * 176 + t];
        simall[t] = s;
        const float* bp = boxes + (size_t)(b * G_ + t) * AN * CH;
        float o = 0.f;
        for (int a = 0; a < AN; a++) o += bp[a * CH + 4];
        ms[t] = o / (float)AN;
    }
    // bb = b_vs . (sum_s py[s][b] + b_ts); H_ == 512 == blockDim
    {
        float yv = b_ts[t];
        #pragma unroll
        for (int s = 0; s < SPL; s++) yv += py[((size_t)s * bs + b) * H_ + t];
        float part = b_vs[t] * yv;
        #pragma unroll
        for (int off = 32; off > 0; off >>= 1) part += __shfl_down(part, off);
        if (lane == 0) redw[w] = part;
    }
    __syncthreads();
    if (t == 0) {
        float s = 0.f;
        #pragma unroll
        for (int ww = 0; ww < 8; ww++) s += redw[ww];
        bbs = s;
    }

    // exact top-k via rank (value desc, index asc) -- matches lax.top_k ties
    if (t < G_) {
        float mv = ms[t];
        int rank = 0;
        for (int g = 0; g < G_; g++) {
            float o = ms[g];
            rank += (int)((o > mv) | ((o == mv) & (g < t)));
        }
        if (rank < k) selg[rank] = t;
    }
    __syncthreads();

    if (t < k) simv[t] = simall[selg[t]];
    __syncthreads();

    if (t == 0) {
        float best = -FLT_MAX; int br = 0;
        for (int r = 0; r < k; r++) if (simv[r] > best) { best = simv[r]; br = r; }
        int gs = selg[br];
        const float* bp = boxes + (size_t)(b * G_ + gs) * AN * CH;
        float bo = -FLT_MAX; int ai = 0;
        for (int a = 0; a < AN; a++) { float o = bp[a * CH + 4]; if (o > bo) { bo = o; ai = a; } }
        float cx = bp[ai * CH + 0], cy = bp[ai * CH + 1];
        float ww = bp[ai * CH + 2], hh = bp[ai * CH + 3];
        float x1 = cx - ww * 0.5f, y1 = cy - hh * 0.5f;
        out_box[(size_t)b * CH + 0] = x1;
        out_box[(size_t)b * CH + 1] = y1;
        out_box[(size_t)b * CH + 2] = x1 + ww;
        out_box[(size_t)b * CH + 3] = y1 + hh;
        for (int c = 4; c < CH; c++) out_box[(size_t)b * CH + c] = bp[ai * CH + c];
        out_max[b] = best + bbs;
        selp[0] = gs; selp[1] = ai;
    }
    __syncthreads();
    if (t < CM) {
        out_mask[(size_t)b * CM + t] =
            masks[((size_t)(b * G_ + selp[0]) * AN + selp[1]) * CM + t];
    }
}

extern "C" void kernel_launch(void* const* d_in, const int* in_sizes, int n_in,
                              void* d_out, int out_size, void* d_ws, size_t ws_size,
                              hipStream_t stream)
{
    const float* boxes = (const float*)d_in[0];
    const float* masks = (const float*)d_in[1];
    const float* feat  = (const float*)d_in[2];
    const float* lang  = (const float*)d_in[3];
    const float* W_vs  = (const float*)d_in[4];
    const float* b_vs  = (const float*)d_in[5];
    const float* W_ts  = (const float*)d_in[6];
    const float* b_ts  = (const float*)d_in[7];
    const int*   kptr  = (const int*)d_in[8];

    int H  = in_sizes[5];                  // 512
    int D  = in_sizes[4] / H;              // 1024
    int bs = in_sizes[3] / H;              // 256
    int AN = 3;
    int CH = in_sizes[0] / (bs * G_ * AN); // 5
    int CM = in_sizes[1] / (bs * G_ * AN); // 32

    float* py = (float*)d_ws;                     // SPL*bs*H
    float* pz = py + (size_t)SPL * bs * H;        // SPL*bs*D

    float* out_box  = (float*)d_out;
    float* out_mask = out_box + (size_t)bs * CH;
    float* out_max  = out_mask + (size_t)bs * CM;

    // py = split-K partials of lang @ W_ts
    dim3 g1(H / GBN, bs / GBM, SPL);
    gemm_splitk<<<g1, 256, 0, stream>>>(lang, W_ts, py, bs, H, H);
    // pz = split-K partials of (sum py + b_ts) @ W_vs^T
    dim3 g2(D / GBN, bs / GBM, SPL);
    gemm2_fused<<<g2, 256, 0, stream>>>(py, b_ts, W_vs, pz, bs, D, H);
    // whole-batch feat.z (register loads) + finalize, one block per batch
    feat_final<<<bs, 512, 0, stream>>>(feat, pz, boxes, masks, py, b_ts, b_vs,
                                       kptr, out_box, out_mask, out_max,
                                       bs, AN, CH, CM);
}

// Round 13
// 56.481 us; speedup vs baseline: 1.3304x; 1.3304x over previous
//
#include <hip/hip_runtime.h>
#include <cfloat>
#include <cstdint>

#define GBM 64
#define GBN 64
#define GBK 64
#define GPAD 68     // 68*4=272B rows: 16B-aligned for b128 frags

#define G_    169
#define D_    1024
#define H_    512
#define NW    8     // waves per feat_final block
#define ROWG  8     // rows per staged group
#define NGRP  16    // groups per wave (128 rows)
#define GRPF  1352  // ROWG*G_ floats per group
#define NV    338   // GRPF/4 float4 per group
#define NBUF  3
#define SPL   8     // split-K slices

typedef unsigned int u32;

__device__ __forceinline__ void gload_lds16(const float* g, float* l) {
    __builtin_amdgcn_global_load_lds(
        (const __attribute__((address_space(1))) u32*)g,
        (__attribute__((address_space(3))) u32*)l, 16, 0, 0);
}

// stage one 8x169 group: 6 gload_lds16 per wave (j=5 masked; still 6 vmcnt)
__device__ __forceinline__ void stage_group(const float* gsrc, float* ldsbase, int lane) {
    #pragma unroll
    for (int j = 0; j < 6; j++) {
        int idx = j * 64 + lane;
        if (idx < NV)
            gload_lds16(gsrc + 4 * idx, ldsbase + j * 256);
    }
}

// ---- split-K GEMM: py[s][M][N] partial of A[M,K] @ B[K,N], one 64^3 tile/block
__global__ __launch_bounds__(256) void gemm_splitk(
    const float* __restrict__ A, const float* __restrict__ B,
    float* __restrict__ Cpart, int M, int N, int K)
{
    __shared__ __align__(16) float Asm[GBK][GPAD];
    __shared__ __align__(16) float Bsm[GBK][GPAD];
    int t  = threadIdx.x;
    int m0 = blockIdx.y * GBM, n0 = blockIdx.x * GBN;
    int ks = blockIdx.z * GBK;

    #pragma unroll
    for (int i = 0; i < 4; i++) {
        int v = t + 256 * i;
        int m = v >> 4, k4 = (v & 15) * 4;
        float4 x = *(const float4*)&A[(size_t)(m0 + m) * K + ks + k4];
        Asm[k4 + 0][m] = x.x; Asm[k4 + 1][m] = x.y;
        Asm[k4 + 2][m] = x.z; Asm[k4 + 3][m] = x.w;
    }
    #pragma unroll
    for (int i = 0; i < 4; i++) {
        int v = t + 256 * i;
        int r = v >> 4, c4 = (v & 15) * 4;
        *(float4*)&Bsm[r][c4] = *(const float4*)&B[(size_t)(ks + r) * N + n0 + c4];
    }
    __syncthreads();

    int r4 = (t >> 4) * 4, c4 = (t & 15) * 4;
    float acc[4][4] = {{0.f}};
    #pragma unroll
    for (int kk = 0; kk < GBK; kk++) {
        float4 a = *(const float4*)&Asm[kk][r4];
        float4 b = *(const float4*)&Bsm[kk][c4];
        float av[4] = {a.x, a.y, a.z, a.w};
        float bv[4] = {b.x, b.y, b.z, b.w};
        #pragma unroll
        for (int i = 0; i < 4; i++)
            #pragma unroll
            for (int j = 0; j < 4; j++) acc[i][j] += av[i] * bv[j];
    }
    float* Cp = Cpart + (size_t)blockIdx.z * M * N;
    #pragma unroll
    for (int i = 0; i < 4; i++) {
        float4 v = {acc[i][0], acc[i][1], acc[i][2], acc[i][3]};
        *(float4*)&Cp[(size_t)(m0 + r4 + i) * N + n0 + c4] = v;
    }
}

// ---- feat_final: y from py; z computed per-wave inline (W_vs from L2);
// feat streamed via per-wave DMA pipeline with counted vmcnt; finalize. ------
__global__ __launch_bounds__(512) void feat_final(
    const float* __restrict__ feat, const float* __restrict__ py,
    const float* __restrict__ W_vs,
    const float* __restrict__ boxes, const float* __restrict__ masks,
    const float* __restrict__ b_ts, const float* __restrict__ b_vs,
    const int* __restrict__ kptr,
    float* __restrict__ out_box, float* __restrict__ out_mask,
    float* __restrict__ out_max,
    int bs, int AN, int CH, int CM)
{
    __shared__ __align__(16) float buf[NW][NBUF][GRPF];   // ~130 KB
    __shared__ __align__(16) float ys[H_];
    __shared__ float accw[NW * 176];
    __shared__ float simall[176];
    __shared__ float ms[176];
    __shared__ int   selg[176];
    __shared__ float simv[176];
    __shared__ float redw[NW];
    __shared__ float bbs;
    __shared__ int   selp[2];

    const int b = blockIdx.x;
    const int t = threadIdx.x;
    const int w = t >> 6, lane = t & 63;

    // ---- y = sum_s py[s][b] + b_ts (512 threads, one h each) ----
    {
        float yv = b_ts[t];
        #pragma unroll
        for (int s = 0; s < SPL; s++) yv += py[((size_t)s * bs + b) * H_ + t];
        ys[t] = yv;
    }
    __syncthreads();

    // lane's y slice into regs: offsets (lane&7)*4 + j*32, j=0..15 (covers 512)
    float4 yreg[16];
    #pragma unroll
    for (int j = 0; j < 16; j++)
        yreg[j] = *(const float4*)&ys[(lane & 7) * 4 + j * 32];

    // ---- DMA prologue ----
    const float* gsrc = feat + ((size_t)b * D_ + (size_t)w * 128) * G_;
    stage_group(gsrc,        buf[w][0], lane);   // 6 outstanding
    stage_group(gsrc + GRPF, buf[w][1], lane);   // 12 outstanding

    float acc0 = 0.f, acc1 = 0.f, acc2 = 0.f;
    const bool g2 = lane < (G_ - 128);            // 41 lanes
    for (int gi = 0; gi < NGRP; gi++) {
        // z chunk gi: 8 rows of W_vs, lane covers row (lane>>3), seg (lane&7)
        const float* Wp = W_vs + (size_t)(w * 128 + gi * 8 + (lane >> 3)) * H_;
        float4 wr[16];
        #pragma unroll
        for (int j = 0; j < 16; j++)
            wr[j] = *(const float4*)&Wp[(lane & 7) * 4 + j * 32];
        __builtin_amdgcn_sched_barrier(0);
        if (gi + 2 < NGRP)
            stage_group(gsrc + (size_t)(gi + 2) * GRPF, buf[w][(gi + 2) % NBUF], lane);
        __builtin_amdgcn_sched_barrier(0);
        if (gi + 2 < NGRP)
            asm volatile("s_waitcnt vmcnt(6)" ::: "memory");  // W_vs + group gi done
        else
            asm volatile("s_waitcnt vmcnt(0)" ::: "memory");
        __builtin_amdgcn_sched_barrier(0);

        float zpart = 0.f;
        #pragma unroll
        for (int j = 0; j < 16; j++)
            zpart += wr[j].x * yreg[j].x + wr[j].y * yreg[j].y
                   + wr[j].z * yreg[j].z + wr[j].w * yreg[j].w;
        zpart += __shfl_xor(zpart, 1);
        zpart += __shfl_xor(zpart, 2);
        zpart += __shfl_xor(zpart, 4);   // all lanes in 8-group hold z[row]

        const float* bp = buf[w][gi % NBUF];
        #pragma unroll
        for (int r = 0; r < ROWG; r++) {
            float zv = __shfl(zpart, r << 3, 64);
            acc0 += bp[r * G_ + lane] * zv;
            acc1 += bp[r * G_ + lane + 64] * zv;
            if (g2) acc2 += bp[r * G_ + lane + 128] * zv;
        }
    }
    accw[w * 176 + lane]      = acc0;
    accw[w * 176 + lane + 64] = acc1;
    if (g2) accw[w * 176 + lane + 128] = acc2;
    __syncthreads();

    // ======================= finalize for batch b =========================
    int k = *kptr; if (k > G_) k = G_;

    if (t < G_) {
        float s = 0.f;
        #pragma unroll
        for (int ww = 0; ww < NW; ww++) s += accw[ww * 176 + t];
        simall[t] = s;
        const float* bp = boxes + (size_t)(b * G_ + t) * AN * CH;
        float o = 0.f;
        for (int a = 0; a < AN; a++) o += bp[a * CH + 4];
        ms[t] = o / (float)AN;
    }
    // bb = b_vs . y
    {
        float part = b_vs[t] * ys[t];
        #pragma unroll
        for (int off = 32; off > 0; off >>= 1) part += __shfl_down(part, off);
        if (lane == 0) redw[w] = part;
    }
    __syncthreads();
    if (t == 0) {
        float s = 0.f;
        #pragma unroll
        for (int ww = 0; ww < NW; ww++) s += redw[ww];
        bbs = s;
    }

    // exact top-k via rank (value desc, index asc) -- matches lax.top_k ties
    if (t < G_) {
        float mv = ms[t];
        int rank = 0;
        for (int g = 0; g < G_; g++) {
            float o = ms[g];
            rank += (int)((o > mv) | ((o == mv) & (g < t)));
        }
        if (rank < k) selg[rank] = t;
    }
    __syncthreads();

    if (t < k) simv[t] = simall[selg[t]];
    __syncthreads();

    if (t == 0) {
        float best = -FLT_MAX; int br = 0;
        for (int r = 0; r < k; r++) if (simv[r] > best) { best = simv[r]; br = r; }
        int gs = selg[br];
        const float* bp = boxes + (size_t)(b * G_ + gs) * AN * CH;
        float bo = -FLT_MAX; int ai = 0;
        for (int a = 0; a < AN; a++) { float o = bp[a * CH + 4]; if (o > bo) { bo = o; ai = a; } }
        float cx = bp[ai * CH + 0], cy = bp[ai * CH + 1];
        float ww = bp[ai * CH + 2], hh = bp[ai * CH + 3];
        float x1 = cx - ww * 0.5f, y1 = cy - hh * 0.5f;
        out_box[(size_t)b * CH + 0] = x1;
        out_box[(size_t)b * CH + 1] = y1;
        out_box[(size_t)b * CH + 2] = x1 + ww;
        out_box[(size_t)b * CH + 3] = y1 + hh;
        for (int c = 4; c < CH; c++) out_box[(size_t)b * CH + c] = bp[ai * CH + c];
        out_max[b] = best + bbs;
        selp[0] = gs; selp[1] = ai;
    }
    __syncthreads();
    if (t < CM) {
        out_mask[(size_t)b * CM + t] =
            masks[((size_t)(b * G_ + selp[0]) * AN + selp[1]) * CM + t];
    }
}

extern "C" void kernel_launch(void* const* d_in, const int* in_sizes, int n_in,
                              void* d_out, int out_size, void* d_ws, size_t ws_size,
                              hipStream_t stream)
{
    const float* boxes = (const float*)d_in[0];
    const float* masks = (const float*)d_in[1];
    const float* feat  = (const float*)d_in[2];
    const float* lang  = (const float*)d_in[3];
    const float* W_vs  = (const float*)d_in[4];
    const float* b_vs  = (const float*)d_in[5];
    const float* W_ts  = (const float*)d_in[6];
    const float* b_ts  = (const float*)d_in[7];
    const int*   kptr  = (const int*)d_in[8];

    int H  = in_sizes[5];                  // 512
    int bs = in_sizes[3] / H;              // 256
    int AN = 3;
    int CH = in_sizes[0] / (bs * G_ * AN); // 5
    int CM = in_sizes[1] / (bs * G_ * AN); // 32

    float* py = (float*)d_ws;              // SPL*bs*H

    float* out_box  = (float*)d_out;
    float* out_mask = out_box + (size_t)bs * CH;
    float* out_max  = out_mask + (size_t)bs * CM;

    // py = split-K partials of lang @ W_ts
    dim3 g1(H / GBN, bs / GBM, SPL);
    gemm_splitk<<<g1, 256, 0, stream>>>(lang, W_ts, py, bs, H, H);
    // y + in-wave z + feat stream + finalize, one block per batch
    feat_final<<<bs, 512, 0, stream>>>(feat, py, W_vs, boxes, masks, b_ts, b_vs,
                                       kptr, out_box, out_mask, out_max,
                                       bs, AN, CH, CM);
}